// Round 1
// baseline (528.066 us; speedup 1.0000x reference)
//
#include <hip/hip_runtime.h>

#define NPOINTS 500000
#define DIM 64
#define KC 512
#define BLK 256

// One thread per point. Centroids are indexed only by loop counters
// (wave-uniform) -> compiler emits s_load scalar broadcasts; the inner
// loop is pure v_fmac_f32 with one SGPR operand. c2[k] is computed
// cooperatively per block into LDS (0.4% overhead, avoids d_ws/2nd kernel).
__global__ __launch_bounds__(BLK) void KMeans_assign_kernel(
    const float* __restrict__ x, const float* __restrict__ c,
    int* __restrict__ out, int n)
{
    __shared__ float sc2[KC];

    // Cooperative centroid-norm precompute (all threads participate; no
    // early return before __syncthreads).
    for (int k = threadIdx.x; k < KC; k += BLK) {
        const float* crow = c + k * DIM;
        float s0 = 0.f, s1 = 0.f, s2 = 0.f, s3 = 0.f;
        #pragma unroll
        for (int d = 0; d < DIM; d += 4) {
            s0 = fmaf(crow[d + 0], crow[d + 0], s0);
            s1 = fmaf(crow[d + 1], crow[d + 1], s1);
            s2 = fmaf(crow[d + 2], crow[d + 2], s2);
            s3 = fmaf(crow[d + 3], crow[d + 3], s3);
        }
        sc2[k] = (s0 + s1) + (s2 + s3);
    }
    __syncthreads();

    int i = blockIdx.x * BLK + threadIdx.x;
    if (i >= n) return;

    // Load this point's 64 floats into registers (float4 x16).
    float xr[DIM];
    const float4* xv = (const float4*)(x + (size_t)i * DIM);
    #pragma unroll
    for (int j = 0; j < DIM / 4; ++j) {
        float4 v = xv[j];
        xr[4 * j + 0] = v.x;
        xr[4 * j + 1] = v.y;
        xr[4 * j + 2] = v.z;
        xr[4 * j + 3] = v.w;
    }

    float x20 = 0.f, x21 = 0.f, x22 = 0.f, x23 = 0.f;
    #pragma unroll
    for (int d = 0; d < DIM; d += 4) {
        x20 = fmaf(xr[d + 0], xr[d + 0], x20);
        x21 = fmaf(xr[d + 1], xr[d + 1], x21);
        x22 = fmaf(xr[d + 2], xr[d + 2], x22);
        x23 = fmaf(xr[d + 3], xr[d + 3], x23);
    }
    const float x2 = (x20 + x21) + (x22 + x23);

    float best = 3.402823466e38f;
    int   bi   = 0;
    for (int k = 0; k < KC; ++k) {
        const float* crow = c + k * DIM;  // uniform address -> s_load
        float d0 = 0.f, d1 = 0.f, d2a = 0.f, d3 = 0.f;
        #pragma unroll
        for (int d = 0; d < DIM; d += 4) {
            d0  = fmaf(crow[d + 0], xr[d + 0], d0);
            d1  = fmaf(crow[d + 1], xr[d + 1], d1);
            d2a = fmaf(crow[d + 2], xr[d + 2], d2a);
            d3  = fmaf(crow[d + 3], xr[d + 3], d3);
        }
        const float dot = (d0 + d1) + (d2a + d3);
        // Same formula/order as reference: (x2 + c2) - 2*dot, clamp 0.
        float d2 = (x2 + sc2[k]) - 2.0f * dot;
        d2 = fmaxf(d2, 0.0f);
        // First-index tie-break like jnp.argmin: strict <.
        const bool lt = d2 < best;
        best = lt ? d2 : best;
        bi   = lt ? k  : bi;
    }
    out[i] = bi;
}

extern "C" void kernel_launch(void* const* d_in, const int* in_sizes, int n_in,
                              void* d_out, int out_size, void* d_ws, size_t ws_size,
                              hipStream_t stream) {
    const float* x = (const float*)d_in[0];   // [N, 64] fp32
    const float* c = (const float*)d_in[1];   // [512, 64] fp32
    int* out = (int*)d_out;                   // [N] int32 labels
    const int n = in_sizes[0] / DIM;          // 500000

    const int grid = (n + BLK - 1) / BLK;
    KMeans_assign_kernel<<<grid, BLK, 0, stream>>>(x, c, out, n);
}